// Round 4
// baseline (449.160 us; speedup 1.0000x reference)
//
#include <hip/hip_runtime.h>
#include <hip/hip_bf16.h>

typedef unsigned short u16;
typedef short bf16x8 __attribute__((ext_vector_type(8)));
typedef float f32x4 __attribute__((ext_vector_type(4)));

#define CC 512

__device__ __forceinline__ float gelu_tanh(float x) {
    float x3 = x * x * x;
    float z  = 0.7978845608028654f * (x + 0.044715f * x3);
    float e  = __expf(2.0f * z);
    float th = 1.0f - 2.0f / (e + 1.0f);
    return 0.5f * x * (1.0f + th);
}

__device__ __forceinline__ u16 f2bf(float f) {
    union { float f; unsigned u; } v; v.f = f;
    unsigned r = v.u + 0x7fff + ((v.u >> 16) & 1);
    return (u16)(r >> 16);
}
__device__ __forceinline__ float bf2f(u16 h) {
    union { unsigned u; float f; } v; v.u = ((unsigned)h) << 16; return v.f;
}

// ---------------- conv0 + per-(b,c) partial stats --------------------------
__global__ __launch_bounds__(256) void conv0_stats(
    const float* __restrict__ x, const float* __restrict__ w0,
    float* __restrict__ part) {            // [b*512+c][32]{s,q}
    const int chunk = blockIdx.x, b = blockIdx.y;
    const int t0 = chunk * 250;
    __shared__ float xs[250 * 5 + 10];
    __shared__ float w0s[512 * 10];
    for (int i = threadIdx.x; i < 1260; i += 256) {
        int gi = t0 * 5 + i;
        xs[i] = (gi < 40000) ? x[b * 40000 + gi] : 0.0f;
    }
    for (int i = threadIdx.x; i < 5120; i += 256) w0s[i] = w0[i];
    __syncthreads();
    const int nt = min(250, 7999 - t0);
    for (int cc = 0; cc < 2; ++cc) {
        const int c = threadIdx.x * 2 + cc;
        const float* wr = &w0s[c * 10];
        float s = 0.0f, q = 0.0f;
        for (int t = 0; t < nt; ++t) {
            float a = 0.0f;
#pragma unroll
            for (int j = 0; j < 10; ++j) a = fmaf(wr[j], xs[t * 5 + j], a);
            s += a; q += a * a;
        }
        float* p = part + ((size_t)(b * 512 + c) * 32 + chunk) * 2;
        p[0] = s; p[1] = q;
    }
}

__global__ __launch_bounds__(256) void stats_finalize(
    const float* __restrict__ part, float* __restrict__ stats) {
    const int row = blockIdx.x * 256 + threadIdx.x;   // 0..4095
    const float* p = part + (size_t)row * 32 * 2;
    float s = 0.0f, q = 0.0f;
    for (int k = 0; k < 32; ++k) { s += p[k * 2]; q += p[k * 2 + 1]; }
    float mean = s / 7999.0f;
    float var  = fmaxf(q / 7999.0f - mean * mean, 0.0f);
    stats[row * 2]     = mean;
    stats[row * 2 + 1] = rsqrtf(var + 1e-5f);
}

// ---------------- conv0 + norm + gelu -> bf16 act [b][8320][512] -----------
__global__ __launch_bounds__(256) void conv0_apply(
    const float* __restrict__ x, const float* __restrict__ w0,
    const float* __restrict__ stats, const float* __restrict__ gsc,
    const float* __restrict__ gbi, u16* __restrict__ actG) {
    const int t0 = blockIdx.x * 32, b = blockIdx.y;
    __shared__ float xs[32 * 5 + 16];
    __shared__ float w0s[512 * 10];
    __shared__ float A[512], Bb[512];
    for (int i = threadIdx.x; i < 170; i += 256) {
        int gi = t0 * 5 + i;
        xs[i] = (gi < 40000) ? x[b * 40000 + gi] : 0.0f;
    }
    for (int i = threadIdx.x; i < 5120; i += 256) w0s[i] = w0[i];
    for (int c = threadIdx.x; c < 512; c += 256) {
        float m = stats[(b * 512 + c) * 2], r = stats[(b * 512 + c) * 2 + 1];
        float a = r * gsc[c];
        A[c] = a; Bb[c] = gbi[c] - m * a;
    }
    __syncthreads();
    const int c0 = (threadIdx.x & 63) * 8;
    const int wv = threadIdx.x >> 6;          // tt block of 8
    u16 res[8][8];
#pragma unroll
    for (int q = 0; q < 8; ++q) {
        const int c = c0 + q;
        float wreg[10];
#pragma unroll
        for (int j = 0; j < 10; ++j) wreg[j] = w0s[c * 10 + j];
        const float Ar = A[c], Br = Bb[c];
#pragma unroll
        for (int u = 0; u < 8; ++u) {
            const int tt = wv * 8 + u;
            float a = 0.0f;
#pragma unroll
            for (int j = 0; j < 10; ++j) a = fmaf(wreg[j], xs[tt * 5 + j], a);
            res[u][q] = f2bf(gelu_tanh(fmaf(a, Ar, Br)));
        }
    }
#pragma unroll
    for (int u = 0; u < 8; ++u) {
        const int t = t0 + wv * 8 + u;
        union { u16 s[8]; uint4 v; } pk;
#pragma unroll
        for (int q = 0; q < 8; ++q) pk.s[q] = (t < 7999) ? res[u][q] : (u16)0;
        *(uint4*)(actG + ((size_t)b * 8320 + t) * 512 + c0) = pk.v;
    }
}

// ---------------- weight pre-transform (hi only), batched ------------------
// Layout: [cob(8 x 64co)][cit(16)][co(64)][WROW=32K+8]
template <int K, int NL>
struct WtBatch { const float* src[NL]; u16* dst[NL]; };

template <int K, int NL>
__global__ __launch_bounds__(256) void wt_transform(WtBatch<K, NL> a) {
    constexpr int WROW = 32 * K + 8;
    const int cit = blockIdx.x, cob = blockIdx.y, l = blockIdx.z;
    const float* w = a.src[l];
    u16* dst = a.dst[l] + ((size_t)(cob * 16 + cit)) * 64 * WROW;
    for (int idx = threadIdx.x; idx < 64 * WROW; idx += 256) {
        const int co = idx / WROW, e = idx - co * WROW;
        u16 hi = 0;
        if (e < 32 * K) {
            const int j = e >> 5, ci = e & 31;
            hi = f2bf(w[((size_t)(cob * 64 + co) * 512 + cit * 32 + ci) * K + j]);
        }
        dst[idx] = hi;
    }
}

// ---------------- MFMA conv (512->512, k=K, stride 2) + gelu ---------------
// Block: 64co x 256t, 4 waves stacked in t (wave = 64co x 64t).
// X (B-operand) read DIRECTLY from global into double-buffered registers.
// W in LDS, double-buffered, 1 barrier per ci-tile.
// 1-D grid, XCD-grouped decode: all 8 co-blocks of a (t-tile,b) share flat%8.
template <int K>
__global__ __launch_bounds__(256, 2) void conv_mfma(
    const u16* __restrict__ act, int capIn,
    const u16* __restrict__ wt,
    u16* __restrict__ outAct, int capOut, int tbShift) {
    constexpr int WROW = 32 * K + 8;
    constexpr int NCH  = 64 * WROW / 8;           // 16B chunks per W buffer

    __shared__ __align__(16) u16 Ws[2][64 * WROW];

    const int tid  = threadIdx.x;
    const int lane = tid & 63;
    const int wv   = tid >> 6;                     // t-quarter 0..3
    const int l15  = lane & 15, l16 = lane >> 4;

    const int flat = blockIdx.x;
    const int xcd  = flat & 7, cob = (flat >> 3) & 7, Gq = flat >> 6;
    const int G    = xcd + (Gq << 3);
    const int t_b  = G & ((1 << tbShift) - 1);
    const int b    = G >> tbShift;
    const int t0   = t_b * 256;

    const u16* wbase = wt + (size_t)cob * (16 * 64 * WROW);

    // X base pointers (bytes), one per t-fragment
    const char* xb[4];
#pragma unroll
    for (int tf = 0; tf < 4; ++tf) {
        const int t = t0 + wv * 64 + tf * 16 + l15;
        xb[tf] = (const char*)act + ((size_t)b * capIn + 2 * t) * 1024 + l16 * 16;
    }

    // W fragment offsets (u16 units), cit-invariant
    int woff[K][4];
#pragma unroll
    for (int j = 0; j < K; ++j)
#pragma unroll
        for (int cf = 0; cf < 4; ++cf)
            woff[j][cf] = (cf * 16 + l15) * WROW + j * 32 + l16 * 8;

    auto stageW = [&](int buf, int cit) {
        const char* p = (const char*)(wbase + (size_t)cit * 64 * WROW);
#pragma unroll
        for (int k = 0; k < (NCH + 255) / 256; ++k) {
            const int cb = wv * 64 + k * 256;
            if (cb < NCH)
                __builtin_amdgcn_global_load_lds(
                    (const __attribute__((address_space(1))) void*)(p + (size_t)(cb + lane) * 16),
                    (__attribute__((address_space(3))) void*)((char*)&Ws[buf][0] + cb * 16),
                    16, 0, 0);
        }
    };

    f32x4 acc[4][4] = {};
    bf16x8 btA[K][4], btB[K][4];

    // prologue: stage W(0), load bt(0)
    stageW(0, 0);
#pragma unroll
    for (int j = 0; j < K; ++j)
#pragma unroll
        for (int tf = 0; tf < 4; ++tf)
            btA[j][tf] = *(const bf16x8*)(xb[tf] + j * 1024);
    __syncthreads();

    auto body = [&](int cit, bf16x8 (&btC)[K][4], bf16x8 (&btN)[K][4]) {
        const int cur = cit & 1;
        if (cit < 15) {
            stageW(cur ^ 1, cit + 1);                 // W prefetch (oldest vmem)
#pragma unroll
            for (int tf = 0; tf < 4; ++tf) xb[tf] += 64;
#pragma unroll
            for (int j = 0; j < K; ++j)               // X prefetch into regs
#pragma unroll
                for (int tf = 0; tf < 4; ++tf)
                    btN[j][tf] = *(const bf16x8*)(xb[tf] + j * 1024);
        }
        const u16* wb = &Ws[cur][0];
#pragma unroll
        for (int j = 0; j < K; ++j) {
            bf16x8 ah[4];
#pragma unroll
            for (int cf = 0; cf < 4; ++cf) ah[cf] = *(const bf16x8*)(wb + woff[j][cf]);
#pragma unroll
            for (int cf = 0; cf < 4; ++cf)
#pragma unroll
                for (int tf = 0; tf < 4; ++tf)
                    acc[cf][tf] = __builtin_amdgcn_mfma_f32_16x16x32_bf16(
                        ah[cf], btC[j][tf], acc[cf][tf], 0, 0, 0);
        }
        __syncthreads();
    };

    for (int cit = 0; cit < 16; cit += 2) {
        body(cit,     btA, btB);
        body(cit + 1, btB, btA);
    }

    // epilogue: gelu + bf16 transposed store [b][t][512]
    u16* ob = outAct + (size_t)b * capOut * 512;
#pragma unroll
    for (int cf = 0; cf < 4; ++cf) {
#pragma unroll
        for (int tf = 0; tf < 4; ++tf) {
            const int tG  = t0 + wv * 64 + tf * 16 + l15;
            const int coG = cob * 64 + cf * 16 + l16 * 4;
            union { u16 s[4]; uint2 v; } pk;
#pragma unroll
            for (int r = 0; r < 4; ++r)
                pk.s[r] = f2bf(gelu_tanh(acc[cf][tf][r]));
            *(uint2*)(ob + (size_t)tG * 512 + coG) = pk.v;
        }
    }
}

// ---------------- time-mean + proj + relu ----------------------------------
__global__ __launch_bounds__(512) void feat_proj_kernel(
    const u16* __restrict__ act, int cap,
    const float* __restrict__ pw, const float* __restrict__ pb,
    float* __restrict__ pfeat) {
    const int b = blockIdx.x;
    __shared__ float feat[CC];
    const int c = threadIdx.x;
    float s = 0.0f;
    for (int t = 0; t < 124; ++t) s += bf2f(act[((size_t)b * cap + t) * 512 + c]);
    feat[c] = s * (1.0f / 124.0f);
    __syncthreads();
    if (threadIdx.x < 256) {
        const int j = threadIdx.x;
        const float* wr = pw + (size_t)j * CC;
        float acc = pb[j];
        for (int cc = 0; cc < CC; ++cc) acc = fmaf(feat[cc], wr[cc], acc);
        pfeat[b * 256 + j] = fmaxf(acc, 0.0f);
    }
}

// ---------------- per-sample classifier MLP --------------------------------
__global__ __launch_bounds__(128) void cls_kernel(
    const float* __restrict__ pfeat, const int* __restrict__ wid,
    const float* __restrict__ w1, const float* __restrict__ b1,
    const float* __restrict__ w2, const float* __restrict__ b2,
    float* __restrict__ out) {
    const int b = blockIdx.x;
    const int id = wid[b];
    __shared__ float pf[256], h1[128];
    for (int d = threadIdx.x; d < 256; d += 128) pf[d] = pfeat[b * 256 + d];
    __syncthreads();
    {
        const int hh = threadIdx.x;
        const float* w1p = w1 + (size_t)id * 256 * 128;
        float s = b1[id * 128 + hh];
        for (int d = 0; d < 256; ++d) s = fmaf(pf[d], w1p[d * 128 + hh], s);
        h1[hh] = fmaxf(s, 0.0f);
    }
    __syncthreads();
    if (threadIdx.x < 5) {
        const float* w2p = w2 + (size_t)id * 128 * 5;
        float s = b2[id * 5 + threadIdx.x];
        for (int hh = 0; hh < 128; ++hh) s = fmaf(h1[hh], w2p[hh * 5 + threadIdx.x], s);
        out[b * 5 + threadIdx.x] = s;
    }
}

// ---------------------------------------------------------------------------
extern "C" void kernel_launch(void* const* d_in, const int* in_sizes, int n_in,
                              void* d_out, int out_size, void* d_ws, size_t ws_size,
                              hipStream_t stream) {
    const float* x   = (const float*)d_in[0];
    const int*   wid = (const int*)d_in[1];
    const float* gsc = (const float*)d_in[2];
    const float* gbi = (const float*)d_in[3];
    const float* pw  = (const float*)d_in[4];
    const float* pb  = (const float*)d_in[5];
    const float* w1  = (const float*)d_in[6];
    const float* b1  = (const float*)d_in[7];
    const float* w2  = (const float*)d_in[8];
    const float* b2  = (const float*)d_in[9];
    const float* cw[7];
    for (int i = 0; i < 7; ++i) cw[i] = (const float*)d_in[10 + i];

    // ---- workspace layout ----
    char* ws = (char*)d_ws;
    const size_t SZ_ACTG = (size_t)8 * 8320 * 512 * 2;
    const size_t SZ_P    = (size_t)8 * 4224 * 512 * 2;
    const size_t SZ_Q    = (size_t)8 * 2176 * 512 * 2;
    u16* actG = (u16*)ws;
    u16* bufP = (u16*)(ws + SZ_ACTG);
    u16* bufQ = (u16*)(ws + SZ_ACTG + SZ_P);
    size_t off = SZ_ACTG + SZ_P + SZ_Q;
    u16* wtbuf[7];
    for (int i = 1; i <= 4; ++i) { wtbuf[i] = (u16*)(ws + off); off += (size_t)8 * 16 * 64 * 104 * 2; }
    for (int i = 5; i <= 6; ++i) { wtbuf[i] = (u16*)(ws + off); off += (size_t)8 * 16 * 64 * 72 * 2; }
    off = (off + 255) & ~(size_t)255;
    float* statsPart = (float*)(ws + off); off += (size_t)4096 * 32 * 2 * 4;
    float* stats     = (float*)(ws + off); off += 4096 * 2 * 4;
    float* pfeat     = (float*)(ws + off); off += 8 * 256 * 4;

    // ---- conv0 + stats + apply ----
    conv0_stats<<<dim3(32, 8), 256, 0, stream>>>(x, cw[0], statsPart);
    stats_finalize<<<dim3(16), 256, 0, stream>>>(statsPart, stats);
    conv0_apply<<<dim3(260, 8), 256, 0, stream>>>(x, cw[0], stats, gsc, gbi, actG);

    // ---- weight pre-transforms (2 launches) ----
    {
        WtBatch<3, 4> a;
        for (int i = 0; i < 4; ++i) { a.src[i] = cw[1 + i]; a.dst[i] = wtbuf[1 + i]; }
        wt_transform<3, 4><<<dim3(16, 8, 4), 256, 0, stream>>>(a);
        WtBatch<2, 2> c;
        for (int i = 0; i < 2; ++i) { c.src[i] = cw[5 + i]; c.dst[i] = wtbuf[5 + i]; }
        wt_transform<2, 2><<<dim3(16, 8, 2), 256, 0, stream>>>(c);
    }

    // ---- conv chain: 1-D grids, nwg = nTb*64, tbShift = log2(nTb) ----
    conv_mfma<3><<<dim3(16 * 64), 256, 0, stream>>>(actG, 8320, wtbuf[1], bufP, 4224, 4);
    conv_mfma<3><<<dim3( 8 * 64), 256, 0, stream>>>(bufP, 4224, wtbuf[2], bufQ, 2176, 3);
    conv_mfma<3><<<dim3( 4 * 64), 256, 0, stream>>>(bufQ, 2176, wtbuf[3], bufP, 4224, 2);
    conv_mfma<3><<<dim3( 2 * 64), 256, 0, stream>>>(bufP, 4224, wtbuf[4], bufQ, 2176, 1);
    conv_mfma<2><<<dim3( 1 * 64), 256, 0, stream>>>(bufQ, 2176, wtbuf[5], bufP, 4224, 0);
    conv_mfma<2><<<dim3( 1 * 64), 256, 0, stream>>>(bufP, 4224, wtbuf[6], bufQ, 2176, 0);

    // ---- tail ----
    feat_proj_kernel<<<dim3(8), 512, 0, stream>>>(bufQ, 2176, pw, pb, pfeat);
    cls_kernel<<<dim3(8), 128, 0, stream>>>(pfeat, wid, w1, b1, w2, b2, (float*)d_out);
}

// Round 5
// 347.644 us; speedup vs baseline: 1.2920x; 1.2920x over previous
//
#include <hip/hip_runtime.h>
#include <hip/hip_bf16.h>

typedef unsigned short u16;
typedef short bf16x8 __attribute__((ext_vector_type(8)));
typedef float f32x4 __attribute__((ext_vector_type(4)));

#define CC 512

__device__ __forceinline__ float gelu_tanh(float x) {
    float x3 = x * x * x;
    float z  = 0.7978845608028654f * (x + 0.044715f * x3);
    float e  = __expf(2.0f * z);
    float th = 1.0f - 2.0f / (e + 1.0f);
    return 0.5f * x * (1.0f + th);
}

__device__ __forceinline__ u16 f2bf(float f) {
    union { float f; unsigned u; } v; v.f = f;
    unsigned r = v.u + 0x7fff + ((v.u >> 16) & 1);
    return (u16)(r >> 16);
}
__device__ __forceinline__ float bf2f(u16 h) {
    union { unsigned u; float f; } v; v.u = ((unsigned)h) << 16; return v.f;
}

// ---------------- conv0 + per-(b,c) partial stats --------------------------
__global__ __launch_bounds__(256) void conv0_stats(
    const float* __restrict__ x, const float* __restrict__ w0,
    float* __restrict__ part) {            // [b*512+c][32]{s,q}
    const int chunk = blockIdx.x, b = blockIdx.y;
    const int t0 = chunk * 250;
    __shared__ float xs[250 * 5 + 10];
    __shared__ float w0s[512 * 10];
    for (int i = threadIdx.x; i < 1260; i += 256) {
        int gi = t0 * 5 + i;
        xs[i] = (gi < 40000) ? x[b * 40000 + gi] : 0.0f;
    }
    for (int i = threadIdx.x; i < 5120; i += 256) w0s[i] = w0[i];
    __syncthreads();
    const int nt = min(250, 7999 - t0);
    for (int cc = 0; cc < 2; ++cc) {
        const int c = threadIdx.x * 2 + cc;
        const float* wr = &w0s[c * 10];
        float s = 0.0f, q = 0.0f;
        for (int t = 0; t < nt; ++t) {
            float a = 0.0f;
#pragma unroll
            for (int j = 0; j < 10; ++j) a = fmaf(wr[j], xs[t * 5 + j], a);
            s += a; q += a * a;
        }
        float* p = part + ((size_t)(b * 512 + c) * 32 + chunk) * 2;
        p[0] = s; p[1] = q;
    }
}

__global__ __launch_bounds__(256) void stats_finalize(
    const float* __restrict__ part, float* __restrict__ stats) {
    const int row = blockIdx.x * 256 + threadIdx.x;   // 0..4095
    const float* p = part + (size_t)row * 32 * 2;
    float s = 0.0f, q = 0.0f;
    for (int k = 0; k < 32; ++k) { s += p[k * 2]; q += p[k * 2 + 1]; }
    float mean = s / 7999.0f;
    float var  = fmaxf(q / 7999.0f - mean * mean, 0.0f);
    stats[row * 2]     = mean;
    stats[row * 2 + 1] = rsqrtf(var + 1e-5f);
}

// ---------------- conv0 + norm + gelu -> bf16 act [b][8320][512] -----------
__global__ __launch_bounds__(256) void conv0_apply(
    const float* __restrict__ x, const float* __restrict__ w0,
    const float* __restrict__ stats, const float* __restrict__ gsc,
    const float* __restrict__ gbi, u16* __restrict__ actG) {
    const int t0 = blockIdx.x * 32, b = blockIdx.y;
    __shared__ float xs[32 * 5 + 16];
    __shared__ float w0s[512 * 10];
    __shared__ float A[512], Bb[512];
    for (int i = threadIdx.x; i < 170; i += 256) {
        int gi = t0 * 5 + i;
        xs[i] = (gi < 40000) ? x[b * 40000 + gi] : 0.0f;
    }
    for (int i = threadIdx.x; i < 5120; i += 256) w0s[i] = w0[i];
    for (int c = threadIdx.x; c < 512; c += 256) {
        float m = stats[(b * 512 + c) * 2], r = stats[(b * 512 + c) * 2 + 1];
        float a = r * gsc[c];
        A[c] = a; Bb[c] = gbi[c] - m * a;
    }
    __syncthreads();
    const int c0 = (threadIdx.x & 63) * 8;
    const int wv = threadIdx.x >> 6;          // tt block of 8
    u16 res[8][8];
#pragma unroll
    for (int q = 0; q < 8; ++q) {
        const int c = c0 + q;
        float wreg[10];
#pragma unroll
        for (int j = 0; j < 10; ++j) wreg[j] = w0s[c * 10 + j];
        const float Ar = A[c], Br = Bb[c];
#pragma unroll
        for (int u = 0; u < 8; ++u) {
            const int tt = wv * 8 + u;
            float a = 0.0f;
#pragma unroll
            for (int j = 0; j < 10; ++j) a = fmaf(wreg[j], xs[tt * 5 + j], a);
            res[u][q] = f2bf(gelu_tanh(fmaf(a, Ar, Br)));
        }
    }
#pragma unroll
    for (int u = 0; u < 8; ++u) {
        const int t = t0 + wv * 8 + u;
        union { u16 s[8]; uint4 v; } pk;
#pragma unroll
        for (int q = 0; q < 8; ++q) pk.s[q] = (t < 7999) ? res[u][q] : (u16)0;
        *(uint4*)(actG + ((size_t)b * 8320 + t) * 512 + c0) = pk.v;
    }
}

// ---------------- weight pre-transform (hi only), batched ------------------
// Layout: [cob(4 x 128co)][cit(16)][co(128)][WROW=32K+8]
template <int K, int NL>
struct WtBatch { const float* src[NL]; u16* dst[NL]; };

template <int K, int NL>
__global__ __launch_bounds__(256) void wt_transform(WtBatch<K, NL> a) {
    constexpr int WROW = 32 * K + 8;
    const int cit = blockIdx.x, cob = blockIdx.y, l = blockIdx.z;
    const float* w = a.src[l];
    u16* dst = a.dst[l] + ((size_t)(cob * 16 + cit)) * 128 * WROW;
    for (int idx = threadIdx.x; idx < 128 * WROW; idx += 256) {
        const int co = idx / WROW, e = idx - co * WROW;
        u16 hi = 0;
        if (e < 32 * K) {
            const int j = e >> 5, ci = e & 31;
            hi = f2bf(w[((size_t)(cob * 128 + co) * 512 + cit * 32 + ci) * K + j]);
        }
        dst[idx] = hi;
    }
}

// ---------------- MFMA conv (512->512, k=K, stride 2) + gelu ---------------
// Block: 128co x TTt, 4 waves (2co x 2t). Single LDS buffer for X and W;
// per ci-tile: ds_read all frags to regs -> barrier -> stage next tile into
// the same buffer (gload_lds) -> MFMA from regs (covers staging latency) ->
// barrier (its implicit vmcnt(0) is exactly the staging wait).
// 1-D grid, XCD-grouped: the 4 cob blocks of one (tb,b) share flat%8 -> XCD.
template <int K, int TT>
__global__ __launch_bounds__(256, (TT == 128 ? 2 : 3)) void conv_mfma(
    const u16* __restrict__ act, int capIn,
    const u16* __restrict__ wt,
    u16* __restrict__ outAct, int capOut, int tbShift) {
    constexpr int WROW = 32 * K + 8;
    constexpr int XH   = TT + 8;                 // x-pair rows (128 B each)
    constexpr int TF   = TT / 32;
    constexpr int NXCH = XH * 8;                 // 16B chunks in X tile
    constexpr int NWCH = 128 * WROW / 8;         // 16B chunks in W tile

    __shared__ __align__(16) u16 Xs[XH * 64];
    __shared__ __align__(16) u16 Ws[128 * WROW];

    const int tid  = threadIdx.x;
    const int lane = tid & 63;
    const int wv   = tid >> 6;
    const int wco  = wv >> 1, wtt = wv & 1;
    const int l15  = lane & 15, l16 = lane >> 4;

    const int flat = blockIdx.x;
    const int xcd  = flat & 7, cob = (flat >> 3) & 3;
    const int G    = xcd + (flat >> 5) * 8;
    const int t_b  = G & ((1 << tbShift) - 1);
    const int b    = G >> tbShift;
    const int t0   = t_b * TT;
    const int x0   = t0 * 2;

    const char* abase = (const char*)(act + (size_t)b * capIn * 512);
    const u16*  wbase = wt + (size_t)cob * (16 * 128 * WROW);

    auto stageX = [&](int cit) {
        const char* asl = abase + cit * 64;
#pragma unroll
        for (int k = 0; k < (NXCH + 255) / 256; ++k) {
            const int cb = wv * 64 + k * 256;
            if (cb < NXCH) {
                const int c  = cb + lane;
                const int xh = c >> 3;
                const int li = ((c & 7) * 16) ^ ((xh & 7) << 4);
                int x = x0 + 2 * xh + (li >> 6);
                x = min(x, capIn - 1);
                __builtin_amdgcn_global_load_lds(
                    (const __attribute__((address_space(1))) void*)(asl + (size_t)x * 1024 + (li & 63)),
                    (__attribute__((address_space(3))) void*)((char*)&Xs[0] + cb * 16),
                    16, 0, 0);
            }
        }
    };
    auto stageW = [&](int cit) {
        const char* p = (const char*)(wbase + (size_t)cit * 128 * WROW);
#pragma unroll
        for (int k = 0; k < (NWCH + 255) / 256; ++k) {
            const int cb = wv * 64 + k * 256;
            if (cb < NWCH)
                __builtin_amdgcn_global_load_lds(
                    (const __attribute__((address_space(1))) void*)(p + (size_t)(cb + lane) * 16),
                    (__attribute__((address_space(3))) void*)((char*)&Ws[0] + cb * 16),
                    16, 0, 0);
        }
    };

    // cit-invariant fragment offsets (bytes for X, u16 for W)
    int xoff[K][TF];
    int woff[K][4];
#pragma unroll
    for (int j = 0; j < K; ++j) {
#pragma unroll
        for (int tf = 0; tf < TF; ++tf) {
            const int tl = wtt * (TT / 2) + tf * 16 + l15;
            const int xl = 2 * tl + j;
            const int xh = xl >> 1, p = xl & 1;
            xoff[j][tf] = xh * 128 + ((p * 64 + l16 * 16) ^ ((xh & 7) << 4));
        }
#pragma unroll
        for (int cf = 0; cf < 4; ++cf)
            woff[j][cf] = (wco * 64 + cf * 16 + l15) * WROW + j * 32 + l16 * 8;
    }

    f32x4 acc[4][TF] = {};

    stageX(0); stageW(0);
    __syncthreads();

#pragma unroll 1
    for (int cit = 0; cit < 16; ++cit) {
        bf16x8 xr[K][TF], wr[K][4];
#pragma unroll
        for (int j = 0; j < K; ++j) {
#pragma unroll
            for (int tf = 0; tf < TF; ++tf)
                xr[j][tf] = *(const bf16x8*)((const char*)&Xs[0] + xoff[j][tf]);
#pragma unroll
            for (int cf = 0; cf < 4; ++cf)
                wr[j][cf] = *(const bf16x8*)(&Ws[0] + woff[j][cf]);
        }
        __syncthreads();                 // all waves done reading (vmcnt already 0)
        if (cit < 15) { stageX(cit + 1); stageW(cit + 1); }
#pragma unroll
        for (int j = 0; j < K; ++j)
#pragma unroll
            for (int cf = 0; cf < 4; ++cf)
#pragma unroll
                for (int tf = 0; tf < TF; ++tf)
                    acc[cf][tf] = __builtin_amdgcn_mfma_f32_16x16x32_bf16(
                        wr[j][cf], xr[j][tf], acc[cf][tf], 0, 0, 0);
        __syncthreads();                 // implicit vmcnt(0): staging landed
    }

    // epilogue: gelu + bf16 transposed store [b][t][512]
    u16* ob = outAct + (size_t)b * capOut * 512;
#pragma unroll
    for (int cf = 0; cf < 4; ++cf) {
#pragma unroll
        for (int tf = 0; tf < TF; ++tf) {
            const int tG  = t0 + wtt * (TT / 2) + tf * 16 + l15;
            const int coG = cob * 128 + wco * 64 + cf * 16 + l16 * 4;
            union { u16 s[4]; uint2 v; } pk;
#pragma unroll
            for (int r = 0; r < 4; ++r)
                pk.s[r] = f2bf(gelu_tanh(acc[cf][tf][r]));
            *(uint2*)(ob + (size_t)tG * 512 + coG) = pk.v;
        }
    }
}

// ---------------- time-mean + proj + relu ----------------------------------
__global__ __launch_bounds__(512) void feat_proj_kernel(
    const u16* __restrict__ act, int cap,
    const float* __restrict__ pw, const float* __restrict__ pb,
    float* __restrict__ pfeat) {
    const int b = blockIdx.x;
    __shared__ float feat[CC];
    const int c = threadIdx.x;
    float s = 0.0f;
    for (int t = 0; t < 124; ++t) s += bf2f(act[((size_t)b * cap + t) * 512 + c]);
    feat[c] = s * (1.0f / 124.0f);
    __syncthreads();
    if (threadIdx.x < 256) {
        const int j = threadIdx.x;
        const float* wr = pw + (size_t)j * CC;
        float acc = pb[j];
        for (int cc = 0; cc < CC; ++cc) acc = fmaf(feat[cc], wr[cc], acc);
        pfeat[b * 256 + j] = fmaxf(acc, 0.0f);
    }
}

// ---------------- per-sample classifier MLP --------------------------------
__global__ __launch_bounds__(128) void cls_kernel(
    const float* __restrict__ pfeat, const int* __restrict__ wid,
    const float* __restrict__ w1, const float* __restrict__ b1,
    const float* __restrict__ w2, const float* __restrict__ b2,
    float* __restrict__ out) {
    const int b = blockIdx.x;
    const int id = wid[b];
    __shared__ float pf[256], h1[128];
    for (int d = threadIdx.x; d < 256; d += 128) pf[d] = pfeat[b * 256 + d];
    __syncthreads();
    {
        const int hh = threadIdx.x;
        const float* w1p = w1 + (size_t)id * 256 * 128;
        float s = b1[id * 128 + hh];
        for (int d = 0; d < 256; ++d) s = fmaf(pf[d], w1p[d * 128 + hh], s);
        h1[hh] = fmaxf(s, 0.0f);
    }
    __syncthreads();
    if (threadIdx.x < 5) {
        const float* w2p = w2 + (size_t)id * 128 * 5;
        float s = b2[id * 5 + threadIdx.x];
        for (int hh = 0; hh < 128; ++hh) s = fmaf(h1[hh], w2p[hh * 5 + threadIdx.x], s);
        out[b * 5 + threadIdx.x] = s;
    }
}

// ---------------------------------------------------------------------------
extern "C" void kernel_launch(void* const* d_in, const int* in_sizes, int n_in,
                              void* d_out, int out_size, void* d_ws, size_t ws_size,
                              hipStream_t stream) {
    const float* x   = (const float*)d_in[0];
    const int*   wid = (const int*)d_in[1];
    const float* gsc = (const float*)d_in[2];
    const float* gbi = (const float*)d_in[3];
    const float* pw  = (const float*)d_in[4];
    const float* pb  = (const float*)d_in[5];
    const float* w1  = (const float*)d_in[6];
    const float* b1  = (const float*)d_in[7];
    const float* w2  = (const float*)d_in[8];
    const float* b2  = (const float*)d_in[9];
    const float* cw[7];
    for (int i = 0; i < 7; ++i) cw[i] = (const float*)d_in[10 + i];

    // ---- workspace layout ----
    char* ws = (char*)d_ws;
    const size_t SZ_ACTG = (size_t)8 * 8320 * 512 * 2;
    const size_t SZ_P    = (size_t)8 * 4224 * 512 * 2;
    const size_t SZ_Q    = (size_t)8 * 2176 * 512 * 2;
    u16* actG = (u16*)ws;
    u16* bufP = (u16*)(ws + SZ_ACTG);
    u16* bufQ = (u16*)(ws + SZ_ACTG + SZ_P);
    size_t off = SZ_ACTG + SZ_P + SZ_Q;
    u16* wtbuf[7];
    for (int i = 1; i <= 4; ++i) { wtbuf[i] = (u16*)(ws + off); off += (size_t)4 * 16 * 128 * 104 * 2; }
    for (int i = 5; i <= 6; ++i) { wtbuf[i] = (u16*)(ws + off); off += (size_t)4 * 16 * 128 * 72 * 2; }
    off = (off + 255) & ~(size_t)255;
    float* statsPart = (float*)(ws + off); off += (size_t)4096 * 32 * 2 * 4;
    float* stats     = (float*)(ws + off); off += 4096 * 2 * 4;
    float* pfeat     = (float*)(ws + off); off += 8 * 256 * 4;

    // ---- conv0 + stats + apply ----
    conv0_stats<<<dim3(32, 8), 256, 0, stream>>>(x, cw[0], statsPart);
    stats_finalize<<<dim3(16), 256, 0, stream>>>(statsPart, stats);
    conv0_apply<<<dim3(260, 8), 256, 0, stream>>>(x, cw[0], stats, gsc, gbi, actG);

    // ---- weight pre-transforms (2 launches) ----
    {
        WtBatch<3, 4> a;
        for (int i = 0; i < 4; ++i) { a.src[i] = cw[1 + i]; a.dst[i] = wtbuf[1 + i]; }
        wt_transform<3, 4><<<dim3(16, 4, 4), 256, 0, stream>>>(a);
        WtBatch<2, 2> c;
        for (int i = 0; i < 2; ++i) { c.src[i] = cw[5 + i]; c.dst[i] = wtbuf[5 + i]; }
        wt_transform<2, 2><<<dim3(16, 4, 2), 256, 0, stream>>>(c);
    }

    // ---- conv chain: 1-D grids, blocks = nTb*4*8, tbShift = log2(nTb) ----
    conv_mfma<3, 128><<<dim3(32 * 32), 256, 0, stream>>>(actG, 8320, wtbuf[1], bufP, 4224, 5);
    conv_mfma<3, 128><<<dim3(16 * 32), 256, 0, stream>>>(bufP, 4224, wtbuf[2], bufQ, 2176, 4);
    conv_mfma<3,  64><<<dim3(16 * 32), 256, 0, stream>>>(bufQ, 2176, wtbuf[3], bufP, 4224, 4);
    conv_mfma<3,  64><<<dim3( 8 * 32), 256, 0, stream>>>(bufP, 4224, wtbuf[4], bufQ, 2176, 3);
    conv_mfma<2,  64><<<dim3( 4 * 32), 256, 0, stream>>>(bufQ, 2176, wtbuf[5], bufP, 4224, 2);
    conv_mfma<2,  64><<<dim3( 2 * 32), 256, 0, stream>>>(bufP, 4224, wtbuf[6], bufQ, 2176, 1);

    // ---- tail ----
    feat_proj_kernel<<<dim3(8), 512, 0, stream>>>(bufQ, 2176, pw, pb, pfeat);
    cls_kernel<<<dim3(8), 128, 0, stream>>>(pfeat, wid, w1, b1, w2, b2, (float*)d_out);
}